// Round 1
// baseline (8322.849 us; speedup 1.0000x reference)
//
#include <hip/hip_runtime.h>
#include <hip/hip_bf16.h>
#include <math.h>

#define HID 128

// ---------------- embedding gather: h[i] = emb[x[i]] ----------------
__global__ __launch_bounds__(256) void embed_k(const int* __restrict__ x,
                                               const float* __restrict__ emb,
                                               float* __restrict__ h, int nnodes) {
    int tid = blockIdx.x * 256 + threadIdx.x;
    int node = tid >> 5;
    int lane = tid & 31;
    if (node >= nnodes) return;
    int tok = x[node];
    ((float4*)h)[node * 32 + lane] = ((const float4*)emb)[tok * 32 + lane];
}

// ---------------- scatter-add: agg[dst] += h[src] over edges ----------------
__global__ __launch_bounds__(256) void scatter_k(const int* __restrict__ src,
                                                 const int* __restrict__ dst,
                                                 const float* __restrict__ h,
                                                 float* __restrict__ agg, int nedges) {
    int tid = blockIdx.x * 256 + threadIdx.x;
    int e = tid >> 5;
    int lane = tid & 31;
    if (e >= nedges) return;
    int s = src[e];
    int d = dst[e];
    float4 v = ((const float4*)h)[s * 32 + lane];
    float* p = agg + (size_t)d * HID + lane * 4;
    unsafeAtomicAdd(p + 0, v.x);
    unsafeAtomicAdd(p + 1, v.y);
    unsafeAtomicAdd(p + 2, v.z);
    unsafeAtomicAdd(p + 3, v.w);
}

// ---------------- fused GRU cell ----------------
// block: 16 nodes x 128 cols; thread: 1 node x 8 cols, 6 accumulators each.
// hout[n][c] = (1-z)*tanh(i_n + r*h_n) + z*h ; r,z = sigmoid(i_*+h_*)
__global__ __launch_bounds__(256) void gru_k(const float* __restrict__ agg,
                                             const float* __restrict__ hin,
                                             float* __restrict__ hout,
                                             const float* __restrict__ Wih,
                                             const float* __restrict__ Whh,
                                             const float* __restrict__ bih,
                                             const float* __restrict__ bhh,
                                             int nnodes) {
    __shared__ float As[16][HID + 4];  // stride 132 floats: 16B-aligned rows, mild bank spread
    __shared__ float Hs[16][HID + 4];
    const int t = threadIdx.x;
    const int mbase = blockIdx.x * 16;
    // stage 16x128 tiles of agg and hin (512 float4, 2 per thread)
    #pragma unroll
    for (int v = 0; v < 2; ++v) {
        int fid = v * 256 + t;
        int row = fid >> 5, c4 = fid & 31;
        int node = mbase + row;
        float4 a = make_float4(0.f, 0.f, 0.f, 0.f);
        float4 hh = make_float4(0.f, 0.f, 0.f, 0.f);
        if (node < nnodes) {
            a  = ((const float4*)agg)[node * 32 + c4];
            hh = ((const float4*)hin)[node * 32 + c4];
        }
        *(float4*)&As[row][c4 * 4] = a;
        *(float4*)&Hs[row][c4 * 4] = hh;
    }
    __syncthreads();

    const int ml = t & 15;          // node within tile
    const int c0 = (t >> 4) * 8;    // 8 output columns

    float acc[6][8];
    #pragma unroll
    for (int i = 0; i < 6; ++i)
        #pragma unroll
        for (int c = 0; c < 8; ++c) acc[i][c] = 0.f;

    for (int kk = 0; kk < HID; kk += 4) {
        float4 a4 = *(const float4*)&As[ml][kk];
        float4 h4 = *(const float4*)&Hs[ml][kk];
        #pragma unroll
        for (int c = 0; c < 8; ++c) {
            const int col = c0 + c;
            float4 wir = *(const float4*)&Wih[(col) * HID + kk];
            float4 wiz = *(const float4*)&Wih[(col + HID) * HID + kk];
            float4 win = *(const float4*)&Wih[(col + 2 * HID) * HID + kk];
            float4 whr = *(const float4*)&Whh[(col) * HID + kk];
            float4 whz = *(const float4*)&Whh[(col + HID) * HID + kk];
            float4 whn = *(const float4*)&Whh[(col + 2 * HID) * HID + kk];
            acc[0][c] += a4.x * wir.x + a4.y * wir.y + a4.z * wir.z + a4.w * wir.w;
            acc[1][c] += a4.x * wiz.x + a4.y * wiz.y + a4.z * wiz.z + a4.w * wiz.w;
            acc[2][c] += a4.x * win.x + a4.y * win.y + a4.z * win.z + a4.w * win.w;
            acc[3][c] += h4.x * whr.x + h4.y * whr.y + h4.z * whr.z + h4.w * whr.w;
            acc[4][c] += h4.x * whz.x + h4.y * whz.y + h4.z * whz.z + h4.w * whz.w;
            acc[5][c] += h4.x * whn.x + h4.y * whn.y + h4.z * whn.z + h4.w * whn.w;
        }
    }

    const int node = mbase + ml;
    if (node < nnodes) {
        #pragma unroll
        for (int c = 0; c < 8; ++c) {
            const int col = c0 + c;
            float ir = acc[0][c] + bih[col];
            float iz = acc[1][c] + bih[col + HID];
            float in_ = acc[2][c] + bih[col + 2 * HID];
            float hr = acc[3][c] + bhh[col];
            float hz = acc[4][c] + bhh[col + HID];
            float hn = acc[5][c] + bhh[col + 2 * HID];
            float r = 1.f / (1.f + expf(-(ir + hr)));
            float z = 1.f / (1.f + expf(-(iz + hz)));
            float n = tanhf(in_ + r * hn);
            hout[(size_t)node * HID + col] = (1.f - z) * n + z * Hs[ml][col];
        }
    }
}

// ---------------- dense: y = x @ W.T + b ----------------
__global__ __launch_bounds__(256) void dense_k(const float* __restrict__ x,
                                               float* __restrict__ y,
                                               const float* __restrict__ W,
                                               const float* __restrict__ b, int nnodes) {
    __shared__ float Xs[16][HID + 4];
    const int t = threadIdx.x;
    const int mbase = blockIdx.x * 16;
    #pragma unroll
    for (int v = 0; v < 2; ++v) {
        int fid = v * 256 + t;
        int row = fid >> 5, c4 = fid & 31;
        int node = mbase + row;
        float4 xv = make_float4(0.f, 0.f, 0.f, 0.f);
        if (node < nnodes) xv = ((const float4*)x)[node * 32 + c4];
        *(float4*)&Xs[row][c4 * 4] = xv;
    }
    __syncthreads();
    const int ml = t & 15;
    const int c0 = (t >> 4) * 8;
    float acc[8];
    #pragma unroll
    for (int c = 0; c < 8; ++c) acc[c] = 0.f;
    for (int kk = 0; kk < HID; kk += 4) {
        float4 a4 = *(const float4*)&Xs[ml][kk];
        #pragma unroll
        for (int c = 0; c < 8; ++c) {
            float4 w = *(const float4*)&W[(c0 + c) * HID + kk];
            acc[c] += a4.x * w.x + a4.y * w.y + a4.z * w.z + a4.w * w.w;
        }
    }
    const int node = mbase + ml;
    if (node < nnodes) {
        #pragma unroll
        for (int c = 0; c < 8; ++c) y[(size_t)node * HID + c0 + c] = acc[c] + b[c0 + c];
    }
}

// ---------------- segment max pool (batch sorted) ----------------
__global__ __launch_bounds__(128) void pool_k(const float* __restrict__ x,
                                              const int* __restrict__ batch,
                                              int nnodes, float* __restrict__ gmax) {
    const int g = blockIdx.x;
    // lower_bound(batch, g) and lower_bound(batch, g+1)
    int lo = 0, hi = nnodes;
    while (lo < hi) { int mid = (lo + hi) >> 1; if (batch[mid] < g) lo = mid + 1; else hi = mid; }
    int start = lo;
    lo = 0; hi = nnodes;
    while (lo < hi) { int mid = (lo + hi) >> 1; if (batch[mid] < g + 1) lo = mid + 1; else hi = mid; }
    int end = lo;
    const int j = threadIdx.x;
    float m0 = -INFINITY, m1 = -INFINITY, m2 = -INFINITY, m3 = -INFINITY;
    int i = start;
    for (; i + 4 <= end; i += 4) {
        m0 = fmaxf(m0, x[(size_t)(i + 0) * HID + j]);
        m1 = fmaxf(m1, x[(size_t)(i + 1) * HID + j]);
        m2 = fmaxf(m2, x[(size_t)(i + 2) * HID + j]);
        m3 = fmaxf(m3, x[(size_t)(i + 3) * HID + j]);
    }
    for (; i < end; ++i) m0 = fmaxf(m0, x[(size_t)i * HID + j]);
    gmax[g * HID + j] = fmaxf(fmaxf(m0, m1), fmaxf(m2, m3));
}

// ---------------- classifier: out[g] = sigmoid(dot(gmax[g], W) + b) ----------------
__global__ __launch_bounds__(128) void clf_k(const float* __restrict__ gmax,
                                             const float* __restrict__ W,
                                             const float* __restrict__ b,
                                             float* __restrict__ out) {
    __shared__ float red[2];
    const int g = blockIdx.x;
    const int t = threadIdx.x;
    float v = gmax[g * HID + t] * W[t];
    #pragma unroll
    for (int off = 32; off >= 1; off >>= 1) v += __shfl_down(v, off, 64);
    if ((t & 63) == 0) red[t >> 6] = v;
    __syncthreads();
    if (t == 0) {
        float s = red[0] + red[1] + b[0];
        out[g] = 1.f / (1.f + expf(-s));
    }
}

extern "C" void kernel_launch(void* const* d_in, const int* in_sizes, int n_in,
                              void* d_out, int out_size, void* d_ws, size_t ws_size,
                              hipStream_t stream) {
    const int* x      = (const int*)d_in[0];
    const int* ei     = (const int*)d_in[1];
    const int* batch  = (const int*)d_in[2];
    const float* emb  = (const float*)d_in[3];
    const float* Wih0 = (const float*)d_in[4];
    const float* Whh0 = (const float*)d_in[5];
    const float* bih0 = (const float*)d_in[6];
    const float* bhh0 = (const float*)d_in[7];
    const float* Wih1 = (const float*)d_in[8];
    const float* Whh1 = (const float*)d_in[9];
    const float* bih1 = (const float*)d_in[10];
    const float* bhh1 = (const float*)d_in[11];
    const float* dW   = (const float*)d_in[12];
    const float* db   = (const float*)d_in[13];
    const float* cW   = (const float*)d_in[14];
    const float* cb   = (const float*)d_in[15];

    const int N = in_sizes[0];          // 100000
    const int E = in_sizes[1] / 2;      // 1600000
    const int NG = out_size;            // 128
    const size_t NH = (size_t)N * HID;  // 12.8M floats

    float* B0 = (float*)d_ws;           // h
    float* B1 = B0 + NH;                // agg
    float* B2 = B1 + NH;                // h'
    float* gmax = B2 + NH;              // 128*128

    const int* esrc = ei;
    const int* edst = ei + E;

    dim3 blk(256);
    int embGrid = (N * 32 + 255) / 256;
    int scatGrid = (E * 32 + 255) / 256;
    int gruGrid = (N + 15) / 16;

    // h = emb[x]
    embed_k<<<embGrid, blk, 0, stream>>>(x, emb, B0, N);

    // layer 0
    hipMemsetAsync(B1, 0, NH * sizeof(float), stream);
    scatter_k<<<scatGrid, blk, 0, stream>>>(esrc, edst, B0, B1, E);
    gru_k<<<gruGrid, blk, 0, stream>>>(B1, B0, B2, Wih0, Whh0, bih0, bhh0, N);

    // layer 1
    hipMemsetAsync(B1, 0, NH * sizeof(float), stream);
    scatter_k<<<scatGrid, blk, 0, stream>>>(esrc, edst, B2, B1, E);
    gru_k<<<gruGrid, blk, 0, stream>>>(B1, B2, B0, Wih1, Whh1, bih1, bhh1, N);

    // dense
    dense_k<<<gruGrid, blk, 0, stream>>>(B0, B2, dW, db, N);

    // pool + classifier
    pool_k<<<NG, dim3(128), 0, stream>>>(B2, batch, N, gmax);
    clf_k<<<NG, dim3(128), 0, stream>>>(gmax, cW, cb, (float*)d_out);
}

// Round 2
// 3162.052 us; speedup vs baseline: 2.6321x; 2.6321x over previous
//
#include <hip/hip_runtime.h>
#include <hip/hip_bf16.h>
#include <math.h>

#define HID 128

// ---------------- embedding gather: h[i] = emb[x[i]] ----------------
__global__ __launch_bounds__(256) void embed_k(const int* __restrict__ x,
                                               const float* __restrict__ emb,
                                               float* __restrict__ h, int nnodes) {
    int tid = blockIdx.x * 256 + threadIdx.x;
    int node = tid >> 5;
    int lane = tid & 31;
    if (node >= nnodes) return;
    int tok = x[node];
    ((float4*)h)[node * 32 + lane] = ((const float4*)emb)[tok * 32 + lane];
}

// ---------------- CSR build ----------------
__global__ __launch_bounds__(256) void hist_k(const int* __restrict__ dst,
                                              int* __restrict__ deg, int nedges) {
    int e = blockIdx.x * 256 + threadIdx.x;
    if (e < nedges) atomicAdd(&deg[dst[e]], 1);
}

// single-block exclusive scan of deg[0..n) -> rowstart[0..n], rowstart[0]=0
__global__ __launch_bounds__(1024) void scan_k(const int* __restrict__ deg,
                                               int* __restrict__ rowstart, int n) {
    __shared__ int wsum[16];
    __shared__ int carry_s, total_s;
    const int t = threadIdx.x;
    const int lane = t & 63, w = t >> 6;
    if (t == 0) { carry_s = 0; rowstart[0] = 0; }
    __syncthreads();
    for (int base = 0; base < n; base += 1024) {
        int i = base + t;
        int v = (i < n) ? deg[i] : 0;
        // wave inclusive scan
        int sum = v;
        #pragma unroll
        for (int off = 1; off < 64; off <<= 1) {
            int o = __shfl_up(sum, off, 64);
            if (lane >= off) sum += o;
        }
        if (lane == 63) wsum[w] = sum;
        __syncthreads();
        if (t == 0) {
            int run = 0;
            #pragma unroll
            for (int k = 0; k < 16; ++k) { int xx = wsum[k]; wsum[k] = run; run += xx; }
            total_s = run;
        }
        __syncthreads();
        int incl = sum + wsum[w];
        int carry = carry_s;
        if (i < n) rowstart[i + 1] = carry + incl;
        __syncthreads();
        if (t == 0) carry_s = carry + total_s;
        __syncthreads();
    }
}

__global__ __launch_bounds__(256) void fill_k(const int* __restrict__ src,
                                              const int* __restrict__ dst,
                                              int* __restrict__ cursor,
                                              int* __restrict__ sorted_src, int nedges) {
    int e = blockIdx.x * 256 + threadIdx.x;
    if (e < nedges) {
        int pos = atomicAdd(&cursor[dst[e]], 1);
        sorted_src[pos] = src[e];
    }
}

// ---------------- gather-aggregate: agg[n] = sum_{e in CSR[n]} h[src[e]] ----------------
__global__ __launch_bounds__(256) void gather_k(const int* __restrict__ rowstart,
                                                const int* __restrict__ sorted_src,
                                                const float* __restrict__ h,
                                                float* __restrict__ agg, int nnodes) {
    int tid = blockIdx.x * 256 + threadIdx.x;
    int node = tid >> 5;
    int lane = tid & 31;
    if (node >= nnodes) return;
    int beg = rowstart[node];
    int end = rowstart[node + 1];
    const float4* hr = (const float4*)h;
    float4 acc = make_float4(0.f, 0.f, 0.f, 0.f);
    float4 acc2 = make_float4(0.f, 0.f, 0.f, 0.f);
    int e = beg;
    for (; e + 2 <= end; e += 2) {
        int s0 = sorted_src[e];
        int s1 = sorted_src[e + 1];
        float4 v0 = hr[s0 * 32 + lane];
        float4 v1 = hr[s1 * 32 + lane];
        acc.x += v0.x; acc.y += v0.y; acc.z += v0.z; acc.w += v0.w;
        acc2.x += v1.x; acc2.y += v1.y; acc2.z += v1.z; acc2.w += v1.w;
    }
    if (e < end) {
        int s0 = sorted_src[e];
        float4 v0 = hr[s0 * 32 + lane];
        acc.x += v0.x; acc.y += v0.y; acc.z += v0.z; acc.w += v0.w;
    }
    acc.x += acc2.x; acc.y += acc2.y; acc.z += acc2.z; acc.w += acc2.w;
    ((float4*)agg)[node * 32 + lane] = acc;
}

// ---------------- fused GRU cell ----------------
__global__ __launch_bounds__(256) void gru_k(const float* __restrict__ agg,
                                             const float* __restrict__ hin,
                                             float* __restrict__ hout,
                                             const float* __restrict__ Wih,
                                             const float* __restrict__ Whh,
                                             const float* __restrict__ bih,
                                             const float* __restrict__ bhh,
                                             int nnodes) {
    __shared__ float As[16][HID + 4];
    __shared__ float Hs[16][HID + 4];
    const int t = threadIdx.x;
    const int mbase = blockIdx.x * 16;
    #pragma unroll
    for (int v = 0; v < 2; ++v) {
        int fid = v * 256 + t;
        int row = fid >> 5, c4 = fid & 31;
        int node = mbase + row;
        float4 a = make_float4(0.f, 0.f, 0.f, 0.f);
        float4 hh = make_float4(0.f, 0.f, 0.f, 0.f);
        if (node < nnodes) {
            a  = ((const float4*)agg)[node * 32 + c4];
            hh = ((const float4*)hin)[node * 32 + c4];
        }
        *(float4*)&As[row][c4 * 4] = a;
        *(float4*)&Hs[row][c4 * 4] = hh;
    }
    __syncthreads();

    const int ml = t & 15;
    const int c0 = (t >> 4) * 8;

    float acc[6][8];
    #pragma unroll
    for (int i = 0; i < 6; ++i)
        #pragma unroll
        for (int c = 0; c < 8; ++c) acc[i][c] = 0.f;

    for (int kk = 0; kk < HID; kk += 4) {
        float4 a4 = *(const float4*)&As[ml][kk];
        float4 h4 = *(const float4*)&Hs[ml][kk];
        #pragma unroll
        for (int c = 0; c < 8; ++c) {
            const int col = c0 + c;
            float4 wir = *(const float4*)&Wih[(col) * HID + kk];
            float4 wiz = *(const float4*)&Wih[(col + HID) * HID + kk];
            float4 win = *(const float4*)&Wih[(col + 2 * HID) * HID + kk];
            float4 whr = *(const float4*)&Whh[(col) * HID + kk];
            float4 whz = *(const float4*)&Whh[(col + HID) * HID + kk];
            float4 whn = *(const float4*)&Whh[(col + 2 * HID) * HID + kk];
            acc[0][c] += a4.x * wir.x + a4.y * wir.y + a4.z * wir.z + a4.w * wir.w;
            acc[1][c] += a4.x * wiz.x + a4.y * wiz.y + a4.z * wiz.z + a4.w * wiz.w;
            acc[2][c] += a4.x * win.x + a4.y * win.y + a4.z * win.z + a4.w * win.w;
            acc[3][c] += h4.x * whr.x + h4.y * whr.y + h4.z * whr.z + h4.w * whr.w;
            acc[4][c] += h4.x * whz.x + h4.y * whz.y + h4.z * whz.z + h4.w * whz.w;
            acc[5][c] += h4.x * whn.x + h4.y * whn.y + h4.z * whn.z + h4.w * whn.w;
        }
    }

    const int node = mbase + ml;
    if (node < nnodes) {
        #pragma unroll
        for (int c = 0; c < 8; ++c) {
            const int col = c0 + c;
            float ir = acc[0][c] + bih[col];
            float iz = acc[1][c] + bih[col + HID];
            float in_ = acc[2][c] + bih[col + 2 * HID];
            float hr = acc[3][c] + bhh[col];
            float hz = acc[4][c] + bhh[col + HID];
            float hn = acc[5][c] + bhh[col + 2 * HID];
            float r = 1.f / (1.f + expf(-(ir + hr)));
            float z = 1.f / (1.f + expf(-(iz + hz)));
            float n = tanhf(in_ + r * hn);
            hout[(size_t)node * HID + col] = (1.f - z) * n + z * Hs[ml][col];
        }
    }
}

// ---------------- dense: y = x @ W.T + b ----------------
__global__ __launch_bounds__(256) void dense_k(const float* __restrict__ x,
                                               float* __restrict__ y,
                                               const float* __restrict__ W,
                                               const float* __restrict__ b, int nnodes) {
    __shared__ float Xs[16][HID + 4];
    const int t = threadIdx.x;
    const int mbase = blockIdx.x * 16;
    #pragma unroll
    for (int v = 0; v < 2; ++v) {
        int fid = v * 256 + t;
        int row = fid >> 5, c4 = fid & 31;
        int node = mbase + row;
        float4 xv = make_float4(0.f, 0.f, 0.f, 0.f);
        if (node < nnodes) xv = ((const float4*)x)[node * 32 + c4];
        *(float4*)&Xs[row][c4 * 4] = xv;
    }
    __syncthreads();
    const int ml = t & 15;
    const int c0 = (t >> 4) * 8;
    float acc[8];
    #pragma unroll
    for (int c = 0; c < 8; ++c) acc[c] = 0.f;
    for (int kk = 0; kk < HID; kk += 4) {
        float4 a4 = *(const float4*)&Xs[ml][kk];
        #pragma unroll
        for (int c = 0; c < 8; ++c) {
            float4 w = *(const float4*)&W[(c0 + c) * HID + kk];
            acc[c] += a4.x * w.x + a4.y * w.y + a4.z * w.z + a4.w * w.w;
        }
    }
    const int node = mbase + ml;
    if (node < nnodes) {
        #pragma unroll
        for (int c = 0; c < 8; ++c) y[(size_t)node * HID + c0 + c] = acc[c] + b[c0 + c];
    }
}

// ---------------- segment max pool (batch sorted) ----------------
__global__ __launch_bounds__(128) void pool_k(const float* __restrict__ x,
                                              const int* __restrict__ batch,
                                              int nnodes, float* __restrict__ gmax) {
    const int g = blockIdx.x;
    int lo = 0, hi = nnodes;
    while (lo < hi) { int mid = (lo + hi) >> 1; if (batch[mid] < g) lo = mid + 1; else hi = mid; }
    int start = lo;
    lo = 0; hi = nnodes;
    while (lo < hi) { int mid = (lo + hi) >> 1; if (batch[mid] < g + 1) lo = mid + 1; else hi = mid; }
    int end = lo;
    const int j = threadIdx.x;
    float m0 = -INFINITY, m1 = -INFINITY, m2 = -INFINITY, m3 = -INFINITY;
    int i = start;
    for (; i + 4 <= end; i += 4) {
        m0 = fmaxf(m0, x[(size_t)(i + 0) * HID + j]);
        m1 = fmaxf(m1, x[(size_t)(i + 1) * HID + j]);
        m2 = fmaxf(m2, x[(size_t)(i + 2) * HID + j]);
        m3 = fmaxf(m3, x[(size_t)(i + 3) * HID + j]);
    }
    for (; i < end; ++i) m0 = fmaxf(m0, x[(size_t)i * HID + j]);
    gmax[g * HID + j] = fmaxf(fmaxf(m0, m1), fmaxf(m2, m3));
}

// ---------------- classifier ----------------
__global__ __launch_bounds__(128) void clf_k(const float* __restrict__ gmax,
                                             const float* __restrict__ W,
                                             const float* __restrict__ b,
                                             float* __restrict__ out) {
    __shared__ float red[2];
    const int g = blockIdx.x;
    const int t = threadIdx.x;
    float v = gmax[g * HID + t] * W[t];
    #pragma unroll
    for (int off = 32; off >= 1; off >>= 1) v += __shfl_down(v, off, 64);
    if ((t & 63) == 0) red[t >> 6] = v;
    __syncthreads();
    if (t == 0) {
        float s = red[0] + red[1] + b[0];
        out[g] = 1.f / (1.f + expf(-s));
    }
}

extern "C" void kernel_launch(void* const* d_in, const int* in_sizes, int n_in,
                              void* d_out, int out_size, void* d_ws, size_t ws_size,
                              hipStream_t stream) {
    const int* x      = (const int*)d_in[0];
    const int* ei     = (const int*)d_in[1];
    const int* batch  = (const int*)d_in[2];
    const float* emb  = (const float*)d_in[3];
    const float* Wih0 = (const float*)d_in[4];
    const float* Whh0 = (const float*)d_in[5];
    const float* bih0 = (const float*)d_in[6];
    const float* bhh0 = (const float*)d_in[7];
    const float* Wih1 = (const float*)d_in[8];
    const float* Whh1 = (const float*)d_in[9];
    const float* bih1 = (const float*)d_in[10];
    const float* bhh1 = (const float*)d_in[11];
    const float* dW   = (const float*)d_in[12];
    const float* db   = (const float*)d_in[13];
    const float* cW   = (const float*)d_in[14];
    const float* cb   = (const float*)d_in[15];

    const int N = in_sizes[0];          // 100000
    const int E = in_sizes[1] / 2;      // 1600000
    const int NG = out_size;            // 128
    const size_t NH = (size_t)N * HID;

    float* B0 = (float*)d_ws;           // h
    float* B1 = B0 + NH;                // agg
    float* B2 = B1 + NH;                // h'
    float* gmax = B2 + NH;              // 128*128
    int* deg        = (int*)(gmax + (size_t)NG * HID);   // N (also reused as cursor? no)
    int* rowstart   = deg + N;                           // N+1
    int* cursor     = rowstart + (N + 1);                // N
    int* sorted_src = cursor + N;                        // E

    const int* esrc = ei;
    const int* edst = ei + E;

    dim3 blk(256);
    int embGrid  = (N * 32 + 255) / 256;
    int edgeGrid = (E + 255) / 256;
    int gathGrid = (N * 32 + 255) / 256;
    int gruGrid  = (N + 15) / 16;

    // h = emb[x]
    embed_k<<<embGrid, blk, 0, stream>>>(x, emb, B0, N);

    // ---- CSR build (once; reused for both layers) ----
    hipMemsetAsync(deg, 0, (size_t)N * sizeof(int), stream);
    hist_k<<<edgeGrid, blk, 0, stream>>>(edst, deg, E);
    scan_k<<<1, dim3(1024), 0, stream>>>(deg, rowstart, N);
    hipMemcpyAsync(cursor, rowstart, (size_t)N * sizeof(int),
                   hipMemcpyDeviceToDevice, stream);
    fill_k<<<edgeGrid, blk, 0, stream>>>(esrc, edst, cursor, sorted_src, E);

    // layer 0
    gather_k<<<gathGrid, blk, 0, stream>>>(rowstart, sorted_src, B0, B1, N);
    gru_k<<<gruGrid, blk, 0, stream>>>(B1, B0, B2, Wih0, Whh0, bih0, bhh0, N);

    // layer 1
    gather_k<<<gathGrid, blk, 0, stream>>>(rowstart, sorted_src, B2, B1, N);
    gru_k<<<gruGrid, blk, 0, stream>>>(B1, B2, B0, Wih1, Whh1, bih1, bhh1, N);

    // dense
    dense_k<<<gruGrid, blk, 0, stream>>>(B0, B2, dW, db, N);

    // pool + classifier
    pool_k<<<NG, dim3(128), 0, stream>>>(B2, batch, N, gmax);
    clf_k<<<NG, dim3(128), 0, stream>>>(gmax, cW, cb, (float*)d_out);
}

// Round 3
// 874.046 us; speedup vs baseline: 9.5222x; 3.6177x over previous
//
#include <hip/hip_runtime.h>
#include <hip/hip_bf16.h>
#include <math.h>

#define HID 128
#define LDA 136  // padded bf16 row stride for LDS A-tiles (2-way bank alias only)

typedef __attribute__((ext_vector_type(8))) short bf16x8;
typedef __attribute__((ext_vector_type(4))) float f32x4;

__device__ __forceinline__ short f2bf(float f) {
    unsigned int u = __float_as_uint(f);
    u += 0x7FFF + ((u >> 16) & 1);   // RNE
    return (short)(u >> 16);
}

// ---------------- embedding gather: h[i] = emb[x[i]] ----------------
__global__ __launch_bounds__(256) void embed_k(const int* __restrict__ x,
                                               const float* __restrict__ emb,
                                               float* __restrict__ h, int nnodes) {
    int tid = blockIdx.x * 256 + threadIdx.x;
    int node = tid >> 5;
    int lane = tid & 31;
    if (node >= nnodes) return;
    int tok = x[node];
    ((float4*)h)[node * 32 + lane] = ((const float4*)emb)[tok * 32 + lane];
}

// ---------------- CSR build ----------------
__global__ __launch_bounds__(256) void hist_k(const int* __restrict__ dst,
                                              int* __restrict__ deg, int nedges) {
    int e = blockIdx.x * 256 + threadIdx.x;
    if (e < nedges) atomicAdd(&deg[dst[e]], 1);
}

__global__ __launch_bounds__(1024) void scan_k(const int* __restrict__ deg,
                                               int* __restrict__ rowstart, int n) {
    __shared__ int wsum[16];
    __shared__ int carry_s, total_s;
    const int t = threadIdx.x;
    const int lane = t & 63, w = t >> 6;
    if (t == 0) { carry_s = 0; rowstart[0] = 0; }
    __syncthreads();
    for (int base = 0; base < n; base += 1024) {
        int i = base + t;
        int v = (i < n) ? deg[i] : 0;
        int sum = v;
        #pragma unroll
        for (int off = 1; off < 64; off <<= 1) {
            int o = __shfl_up(sum, off, 64);
            if (lane >= off) sum += o;
        }
        if (lane == 63) wsum[w] = sum;
        __syncthreads();
        if (t == 0) {
            int run = 0;
            #pragma unroll
            for (int k = 0; k < 16; ++k) { int xx = wsum[k]; wsum[k] = run; run += xx; }
            total_s = run;
        }
        __syncthreads();
        int incl = sum + wsum[w];
        int carry = carry_s;
        if (i < n) rowstart[i + 1] = carry + incl;
        __syncthreads();
        if (t == 0) carry_s = carry + total_s;
        __syncthreads();
    }
}

__global__ __launch_bounds__(256) void fill_k(const int* __restrict__ src,
                                              const int* __restrict__ dst,
                                              int* __restrict__ cursor,
                                              int* __restrict__ sorted_src, int nedges) {
    int e = blockIdx.x * 256 + threadIdx.x;
    if (e < nedges) {
        int pos = atomicAdd(&cursor[dst[e]], 1);
        sorted_src[pos] = src[e];
    }
}

// ---------------- gather-aggregate: agg[n] = sum_{e in CSR[n]} h[src[e]] ----------------
__global__ __launch_bounds__(256) void gather_k(const int* __restrict__ rowstart,
                                                const int* __restrict__ sorted_src,
                                                const float* __restrict__ h,
                                                float* __restrict__ agg, int nnodes) {
    int tid = blockIdx.x * 256 + threadIdx.x;
    int node = tid >> 5;
    int lane = tid & 31;
    if (node >= nnodes) return;
    int beg = rowstart[node];
    int end = rowstart[node + 1];
    const float4* hr = (const float4*)h;
    float4 acc = make_float4(0.f, 0.f, 0.f, 0.f);
    float4 acc2 = make_float4(0.f, 0.f, 0.f, 0.f);
    int e = beg;
    for (; e + 2 <= end; e += 2) {
        int s0 = sorted_src[e];
        int s1 = sorted_src[e + 1];
        float4 v0 = hr[s0 * 32 + lane];
        float4 v1 = hr[s1 * 32 + lane];
        acc.x += v0.x; acc.y += v0.y; acc.z += v0.z; acc.w += v0.w;
        acc2.x += v1.x; acc2.y += v1.y; acc2.z += v1.z; acc2.w += v1.w;
    }
    if (e < end) {
        int s0 = sorted_src[e];
        float4 v0 = hr[s0 * 32 + lane];
        acc.x += v0.x; acc.y += v0.y; acc.z += v0.z; acc.w += v0.w;
    }
    acc.x += acc2.x; acc.y += acc2.y; acc.z += acc2.z; acc.w += acc2.w;
    ((float4*)agg)[node * 32 + lane] = acc;
}

// ---------------- weight pack: fp32 [rows,128] -> bf16 MFMA B-fragments ----------------
// P layout: frag (tile,k0) at ((tile*4+k0)*64 + lane)*8 shorts; lane holds
// W[tile*16 + (lane&15)][k0*32 + (lane>>4)*8 + j], j=0..7. Block = one tile.
__global__ __launch_bounds__(256) void pack_k(const float* __restrict__ WA,
                                              const float* __restrict__ WB,
                                              short* __restrict__ P, int ntilesA) {
    const int tile = blockIdx.x;
    const int t = threadIdx.x;
    const int lane = t & 63, k0 = t >> 6;
    const float* W;
    int row;
    if (tile < ntilesA) { W = WA; row = tile * 16 + (lane & 15); }
    else                { W = WB; row = (tile - ntilesA) * 16 + (lane & 15); }
    const int k = k0 * 32 + (lane >> 4) * 8;
    const float4 f0 = *(const float4*)(W + row * HID + k);
    const float4 f1 = *(const float4*)(W + row * HID + k + 4);
    short4 o0 = make_short4(f2bf(f0.x), f2bf(f0.y), f2bf(f0.z), f2bf(f0.w));
    short4 o1 = make_short4(f2bf(f1.x), f2bf(f1.y), f2bf(f1.z), f2bf(f1.w));
    short* dst = P + ((size_t)(tile * 4 + k0) * 64 + lane) * 8;
    *(short4*)(dst) = o0;
    *(short4*)(dst + 4) = o1;
}

// ---------------- MFMA fused GRU cell ----------------
// Block: 16 nodes. Wave w owns hidden cols [w*32, w*32+32).
// P: 48 tiles (0..23 = Wih cols 0..383, 24..47 = Whh cols 0..383).
__global__ __launch_bounds__(256) void gru_mfma_k(const float* __restrict__ agg,
                                                  const float* __restrict__ hin,
                                                  float* __restrict__ hout,
                                                  const short* __restrict__ P,
                                                  const float* __restrict__ bih,
                                                  const float* __restrict__ bhh,
                                                  int nnodes) {
    __shared__ short As[16 * LDA];
    __shared__ short Hs[16 * LDA];
    __shared__ float Hf[16][132];
    const int t = threadIdx.x;
    const int mbase = blockIdx.x * 16;

    #pragma unroll
    for (int v = 0; v < 2; ++v) {
        int fid = v * 256 + t;
        int row = fid >> 5, c4 = fid & 31;
        int node = mbase + row;
        float4 a = make_float4(0.f, 0.f, 0.f, 0.f);
        float4 hh = make_float4(0.f, 0.f, 0.f, 0.f);
        if (node < nnodes) {
            a  = ((const float4*)agg)[node * 32 + c4];
            hh = ((const float4*)hin)[node * 32 + c4];
        }
        *(short4*)&As[row * LDA + c4 * 4] = make_short4(f2bf(a.x), f2bf(a.y), f2bf(a.z), f2bf(a.w));
        *(short4*)&Hs[row * LDA + c4 * 4] = make_short4(f2bf(hh.x), f2bf(hh.y), f2bf(hh.z), f2bf(hh.w));
        *(float4*)&Hf[row][c4 * 4] = hh;
    }
    __syncthreads();

    const int w = t >> 6, lane = t & 63;
    const int ml = lane & 15, kq = lane >> 4;
    const int j0 = w * 32;

    f32x4 acc[12];  // idx = (mat*3 + gate)*2 + ctt
    #pragma unroll
    for (int i = 0; i < 12; ++i) acc[i] = (f32x4){0.f, 0.f, 0.f, 0.f};

    const short* Pb = P + (size_t)lane * 8;

    #pragma unroll
    for (int k0 = 0; k0 < 4; ++k0) {
        bf16x8 aa = *(const bf16x8*)&As[ml * LDA + k0 * 32 + kq * 8];
        bf16x8 ah = *(const bf16x8*)&Hs[ml * LDA + k0 * 32 + kq * 8];
        #pragma unroll
        for (int m = 0; m < 2; ++m) {
            #pragma unroll
            for (int g = 0; g < 3; ++g) {
                #pragma unroll
                for (int ctt = 0; ctt < 2; ++ctt) {
                    const int tile = m * 24 + g * 8 + (w << 1) + ctt;
                    bf16x8 bb = *(const bf16x8*)(Pb + (size_t)(tile * 4 + k0) * 512);
                    const int idx = (m * 3 + g) * 2 + ctt;
                    acc[idx] = __builtin_amdgcn_mfma_f32_16x16x32_bf16(
                        (m == 0) ? aa : ah, bb, acc[idx], 0, 0, 0);
                }
            }
        }
    }

    #pragma unroll
    for (int ctt = 0; ctt < 2; ++ctt) {
        const int col = j0 + ctt * 16 + ml;
        const float b_ir = bih[col], b_iz = bih[col + 128], b_in = bih[col + 256];
        const float b_hr = bhh[col], b_hz = bhh[col + 128], b_hn = bhh[col + 256];
        #pragma unroll
        for (int r = 0; r < 4; ++r) {
            const int row = kq * 4 + r;
            const int node = mbase + row;
            float ir = acc[0 + ctt][r] + b_ir;
            float iz = acc[2 + ctt][r] + b_iz;
            float in_ = acc[4 + ctt][r] + b_in;
            float hr = acc[6 + ctt][r] + b_hr;
            float hz = acc[8 + ctt][r] + b_hz;
            float hn = acc[10 + ctt][r] + b_hn;
            float rr = 1.f / (1.f + expf(-(ir + hr)));
            float z  = 1.f / (1.f + expf(-(iz + hz)));
            float n  = tanhf(in_ + rr * hn);
            if (node < nnodes)
                hout[(size_t)node * HID + col] = (1.f - z) * n + z * Hf[row][col];
        }
    }
}

// ---------------- MFMA dense: y = x @ W.T + b ----------------
__global__ __launch_bounds__(256) void dense_mfma_k(const float* __restrict__ x,
                                                    float* __restrict__ y,
                                                    const short* __restrict__ P,
                                                    const float* __restrict__ b,
                                                    int nnodes) {
    __shared__ short Xs[16 * LDA];
    const int t = threadIdx.x;
    const int mbase = blockIdx.x * 16;

    #pragma unroll
    for (int v = 0; v < 2; ++v) {
        int fid = v * 256 + t;
        int row = fid >> 5, c4 = fid & 31;
        int node = mbase + row;
        float4 xv = make_float4(0.f, 0.f, 0.f, 0.f);
        if (node < nnodes) xv = ((const float4*)x)[node * 32 + c4];
        *(short4*)&Xs[row * LDA + c4 * 4] = make_short4(f2bf(xv.x), f2bf(xv.y), f2bf(xv.z), f2bf(xv.w));
    }
    __syncthreads();

    const int w = t >> 6, lane = t & 63;
    const int ml = lane & 15, kq = lane >> 4;
    const int j0 = w * 32;

    f32x4 acc[2];
    acc[0] = (f32x4){0.f, 0.f, 0.f, 0.f};
    acc[1] = (f32x4){0.f, 0.f, 0.f, 0.f};
    const short* Pb = P + (size_t)lane * 8;

    #pragma unroll
    for (int k0 = 0; k0 < 4; ++k0) {
        bf16x8 aa = *(const bf16x8*)&Xs[ml * LDA + k0 * 32 + kq * 8];
        #pragma unroll
        for (int ctt = 0; ctt < 2; ++ctt) {
            const int tile = (w << 1) + ctt;
            bf16x8 bb = *(const bf16x8*)(Pb + (size_t)(tile * 4 + k0) * 512);
            acc[ctt] = __builtin_amdgcn_mfma_f32_16x16x32_bf16(aa, bb, acc[ctt], 0, 0, 0);
        }
    }

    #pragma unroll
    for (int ctt = 0; ctt < 2; ++ctt) {
        const int col = j0 + ctt * 16 + ml;
        const float bias = b[col];
        #pragma unroll
        for (int r = 0; r < 4; ++r) {
            const int node = mbase + kq * 4 + r;
            if (node < nnodes)
                y[(size_t)node * HID + col] = acc[ctt][r] + bias;
        }
    }
}

// ---------------- segment max pool (batch sorted) ----------------
__global__ __launch_bounds__(128) void pool_k(const float* __restrict__ x,
                                              const int* __restrict__ batch,
                                              int nnodes, float* __restrict__ gmax) {
    const int g = blockIdx.x;
    int lo = 0, hi = nnodes;
    while (lo < hi) { int mid = (lo + hi) >> 1; if (batch[mid] < g) lo = mid + 1; else hi = mid; }
    int start = lo;
    lo = 0; hi = nnodes;
    while (lo < hi) { int mid = (lo + hi) >> 1; if (batch[mid] < g + 1) lo = mid + 1; else hi = mid; }
    int end = lo;
    const int j = threadIdx.x;
    float m0 = -INFINITY, m1 = -INFINITY, m2 = -INFINITY, m3 = -INFINITY;
    int i = start;
    for (; i + 4 <= end; i += 4) {
        m0 = fmaxf(m0, x[(size_t)(i + 0) * HID + j]);
        m1 = fmaxf(m1, x[(size_t)(i + 1) * HID + j]);
        m2 = fmaxf(m2, x[(size_t)(i + 2) * HID + j]);
        m3 = fmaxf(m3, x[(size_t)(i + 3) * HID + j]);
    }
    for (; i < end; ++i) m0 = fmaxf(m0, x[(size_t)i * HID + j]);
    gmax[g * HID + j] = fmaxf(fmaxf(m0, m1), fmaxf(m2, m3));
}

// ---------------- classifier ----------------
__global__ __launch_bounds__(128) void clf_k(const float* __restrict__ gmax,
                                             const float* __restrict__ W,
                                             const float* __restrict__ b,
                                             float* __restrict__ out) {
    __shared__ float red[2];
    const int g = blockIdx.x;
    const int t = threadIdx.x;
    float v = gmax[g * HID + t] * W[t];
    #pragma unroll
    for (int off = 32; off >= 1; off >>= 1) v += __shfl_down(v, off, 64);
    if ((t & 63) == 0) red[t >> 6] = v;
    __syncthreads();
    if (t == 0) {
        float s = red[0] + red[1] + b[0];
        out[g] = 1.f / (1.f + expf(-s));
    }
}

extern "C" void kernel_launch(void* const* d_in, const int* in_sizes, int n_in,
                              void* d_out, int out_size, void* d_ws, size_t ws_size,
                              hipStream_t stream) {
    const int* x      = (const int*)d_in[0];
    const int* ei     = (const int*)d_in[1];
    const int* batch  = (const int*)d_in[2];
    const float* emb  = (const float*)d_in[3];
    const float* Wih0 = (const float*)d_in[4];
    const float* Whh0 = (const float*)d_in[5];
    const float* bih0 = (const float*)d_in[6];
    const float* bhh0 = (const float*)d_in[7];
    const float* Wih1 = (const float*)d_in[8];
    const float* Whh1 = (const float*)d_in[9];
    const float* bih1 = (const float*)d_in[10];
    const float* bhh1 = (const float*)d_in[11];
    const float* dW   = (const float*)d_in[12];
    const float* db   = (const float*)d_in[13];
    const float* cW   = (const float*)d_in[14];
    const float* cb   = (const float*)d_in[15];

    const int N = in_sizes[0];          // 100000
    const int E = in_sizes[1] / 2;      // 1600000
    const int NG = out_size;            // 128
    const size_t NH = (size_t)N * HID;

    float* B0 = (float*)d_ws;           // h
    float* B1 = B0 + NH;                // agg
    float* B2 = B1 + NH;                // h'
    float* gmax = B2 + NH;              // NG*HID
    short* P0 = (short*)(gmax + (size_t)NG * HID);  // 48*4*64*8 shorts
    short* P1 = P0 + 48 * 4 * 64 * 8;
    short* Pd = P1 + 48 * 4 * 64 * 8;               // 8*4*64*8 shorts
    int* deg        = (int*)(Pd + 8 * 4 * 64 * 8);
    int* rowstart   = deg + N;
    int* cursor     = rowstart + (N + 1);
    int* sorted_src = cursor + N;

    const int* esrc = ei;
    const int* edst = ei + E;

    dim3 blk(256);
    int embGrid  = (N * 32 + 255) / 256;
    int edgeGrid = (E + 255) / 256;
    int gathGrid = (N * 32 + 255) / 256;
    int tileGrid = (N + 15) / 16;

    // weight packing (independent of data path)
    pack_k<<<48, blk, 0, stream>>>(Wih0, Whh0, P0, 24);
    pack_k<<<48, blk, 0, stream>>>(Wih1, Whh1, P1, 24);
    pack_k<<<8,  blk, 0, stream>>>(dW,   dW,   Pd, 8);

    // h = emb[x]
    embed_k<<<embGrid, blk, 0, stream>>>(x, emb, B0, N);

    // CSR build (reused by both layers)
    hipMemsetAsync(deg, 0, (size_t)N * sizeof(int), stream);
    hist_k<<<edgeGrid, blk, 0, stream>>>(edst, deg, E);
    scan_k<<<1, dim3(1024), 0, stream>>>(deg, rowstart, N);
    hipMemcpyAsync(cursor, rowstart, (size_t)N * sizeof(int),
                   hipMemcpyDeviceToDevice, stream);
    fill_k<<<edgeGrid, blk, 0, stream>>>(esrc, edst, cursor, sorted_src, E);

    // layer 0
    gather_k<<<gathGrid, blk, 0, stream>>>(rowstart, sorted_src, B0, B1, N);
    gru_mfma_k<<<tileGrid, blk, 0, stream>>>(B1, B0, B2, P0, bih0, bhh0, N);

    // layer 1
    gather_k<<<gathGrid, blk, 0, stream>>>(rowstart, sorted_src, B2, B1, N);
    gru_mfma_k<<<tileGrid, blk, 0, stream>>>(B1, B2, B0, P1, bih1, bhh1, N);

    // dense
    dense_mfma_k<<<tileGrid, blk, 0, stream>>>(B0, B2, Pd, db, N);

    // pool + classifier
    pool_k<<<NG, dim3(128), 0, stream>>>(B2, batch, N, gmax);
    clf_k<<<NG, dim3(128), 0, stream>>>(gmax, cW, cb, (float*)d_out);
}

// Round 4
// 568.589 us; speedup vs baseline: 14.6377x; 1.5372x over previous
//
#include <hip/hip_runtime.h>
#include <hip/hip_bf16.h>
#include <math.h>

#define HID 128
#define LDA 136   // bf16 LDS row stride (shorts); 272B rows, 16B aligned
#define POOL_P 4

typedef __attribute__((ext_vector_type(8))) short bf16x8;
typedef __attribute__((ext_vector_type(4))) float f32x4;

__device__ __forceinline__ short f2bf(float f) {
    unsigned int u = __float_as_uint(f);
    u += 0x7FFF + ((u >> 16) & 1);   // RNE
    return (short)(u >> 16);
}
__device__ __forceinline__ float bf2f(short s) {
    return __uint_as_float(((unsigned int)(unsigned short)s) << 16);
}

// ---------------- embedding gather: h[i] = bf16(emb[x[i]]) ----------------
__global__ __launch_bounds__(256) void embed_k(const int* __restrict__ x,
                                               const float* __restrict__ emb,
                                               short* __restrict__ h, int nnodes) {
    int tid = blockIdx.x * 256 + threadIdx.x;
    int node = tid >> 4;
    int c8 = tid & 15;
    if (node >= nnodes) return;
    int tok = x[node];
    float4 f0 = ((const float4*)emb)[(size_t)tok * 32 + c8 * 2];
    float4 f1 = ((const float4*)emb)[(size_t)tok * 32 + c8 * 2 + 1];
    bf16x8 o;
    o[0] = f2bf(f0.x); o[1] = f2bf(f0.y); o[2] = f2bf(f0.z); o[3] = f2bf(f0.w);
    o[4] = f2bf(f1.x); o[5] = f2bf(f1.y); o[6] = f2bf(f1.z); o[7] = f2bf(f1.w);
    *(bf16x8*)(h + (size_t)node * HID + c8 * 8) = o;
}

// ---------------- CSR build ----------------
__global__ __launch_bounds__(256) void hist_k(const int* __restrict__ dst,
                                              int* __restrict__ deg, int nedges) {
    int e = blockIdx.x * 256 + threadIdx.x;
    if (e < nedges) atomicAdd(&deg[dst[e]], 1);
}

// exclusive scan of deg[0..n) -> rowstart[0..n] AND cursor[0..n) (copy)
__global__ __launch_bounds__(1024) void scan_k(const int* __restrict__ deg,
                                               int* __restrict__ rowstart,
                                               int* __restrict__ cursor, int n) {
    __shared__ int wsum[16];
    __shared__ int carry_s, total_s;
    const int t = threadIdx.x, lane = t & 63, w = t >> 6;
    if (t == 0) carry_s = 0;
    __syncthreads();
    for (int base = 0; base < n; base += 4096) {
        const int i4 = base + t * 4;
        int4 v = make_int4(0, 0, 0, 0);
        if (i4 + 3 < n) v = *(const int4*)(deg + i4);
        else if (i4 < n) {
            v.x = deg[i4];
            if (i4 + 1 < n) v.y = deg[i4 + 1];
            if (i4 + 2 < n) v.z = deg[i4 + 2];
        }
        int s1 = v.x + v.y, s2 = s1 + v.z, s3 = s2 + v.w;
        int sum = s3;
        #pragma unroll
        for (int off = 1; off < 64; off <<= 1) {
            int o = __shfl_up(sum, off, 64);
            if (lane >= off) sum += o;
        }
        if (lane == 63) wsum[w] = sum;
        __syncthreads();
        if (t == 0) {
            int run = 0;
            #pragma unroll
            for (int k = 0; k < 16; ++k) { int xx = wsum[k]; wsum[k] = run; run += xx; }
            total_s = run;
        }
        __syncthreads();
        const int excl = (sum - s3) + wsum[w] + carry_s;
        if (i4 + 3 < n) {
            int4 o = make_int4(excl, excl + v.x, excl + s1, excl + s2);
            *(int4*)(rowstart + i4) = o;
            *(int4*)(cursor + i4) = o;
        } else if (i4 < n) {
            rowstart[i4] = excl; cursor[i4] = excl;
            if (i4 + 1 < n) { rowstart[i4 + 1] = excl + v.x; cursor[i4 + 1] = excl + v.x; }
            if (i4 + 2 < n) { rowstart[i4 + 2] = excl + s1; cursor[i4 + 2] = excl + s1; }
        }
        __syncthreads();
        if (t == 0) carry_s += total_s;
        __syncthreads();
    }
    if (t == 0) rowstart[n] = carry_s;
}

// XCD-partitioned bucket fill: partition p = blockIdx&7 handles dst range
// [p*npp, p*npp+npp) so all writes to a sorted_src region come from one XCD's
// L2 (round-robin blockIdx->XCD heuristic; perf-only assumption).
__global__ __launch_bounds__(256) void fill_k(const int* __restrict__ src,
                                              const int* __restrict__ dst,
                                              int* __restrict__ cursor,
                                              int* __restrict__ sorted_src,
                                              int nedges, int npp, int nnodes, int nch) {
    const int part = blockIdx.x & 7;
    const int chunk = blockIdx.x >> 3;
    const int lo = part * npp;
    const int hi = min(lo + npp, nnodes);
    const int stride = nch * 256;
    for (int e = chunk * 256 + threadIdx.x; e < nedges; e += stride) {
        int d = dst[e];
        if (d >= lo && d < hi) {
            int pos = atomicAdd(&cursor[d], 1);
            sorted_src[pos] = src[e];
        }
    }
}

// ---------------- gather-aggregate (bf16 h): agg[n] = bf16(sum h[src[e]]) ----------------
__global__ __launch_bounds__(256) void gather_k(const int* __restrict__ rowstart,
                                                const int* __restrict__ sorted_src,
                                                const short* __restrict__ h,
                                                short* __restrict__ agg, int nnodes) {
    int tid = blockIdx.x * 256 + threadIdx.x;
    int node = tid >> 4;
    int l = tid & 15;
    if (node >= nnodes) return;
    int beg = rowstart[node];
    int end = rowstart[node + 1];
    const bf16x8* hr = (const bf16x8*)h;
    float a[8];
    #pragma unroll
    for (int i = 0; i < 8; ++i) a[i] = 0.f;
    int e = beg;
    for (; e + 2 <= end; e += 2) {
        int s0 = sorted_src[e];
        int s1 = sorted_src[e + 1];
        bf16x8 v0 = hr[(size_t)s0 * 16 + l];
        bf16x8 v1 = hr[(size_t)s1 * 16 + l];
        #pragma unroll
        for (int i = 0; i < 8; ++i) a[i] += bf2f(v0[i]);
        #pragma unroll
        for (int i = 0; i < 8; ++i) a[i] += bf2f(v1[i]);
    }
    if (e < end) {
        bf16x8 v0 = hr[(size_t)sorted_src[e] * 16 + l];
        #pragma unroll
        for (int i = 0; i < 8; ++i) a[i] += bf2f(v0[i]);
    }
    bf16x8 o;
    #pragma unroll
    for (int i = 0; i < 8; ++i) o[i] = f2bf(a[i]);
    *(bf16x8*)(agg + (size_t)node * HID + l * 8) = o;
}

// ---------------- weight pack: fp32 [rows,128] -> bf16 MFMA B-fragments ----------------
__global__ __launch_bounds__(256) void pack_k(const float* __restrict__ WA,
                                              const float* __restrict__ WB,
                                              short* __restrict__ P, int ntilesA) {
    const int tile = blockIdx.x;
    const int t = threadIdx.x;
    const int lane = t & 63, k0 = t >> 6;
    const float* W;
    int row;
    if (tile < ntilesA) { W = WA; row = tile * 16 + (lane & 15); }
    else                { W = WB; row = (tile - ntilesA) * 16 + (lane & 15); }
    const int k = k0 * 32 + (lane >> 4) * 8;
    const float4 f0 = *(const float4*)(W + row * HID + k);
    const float4 f1 = *(const float4*)(W + row * HID + k + 4);
    short4 o0 = make_short4(f2bf(f0.x), f2bf(f0.y), f2bf(f0.z), f2bf(f0.w));
    short4 o1 = make_short4(f2bf(f1.x), f2bf(f1.y), f2bf(f1.z), f2bf(f1.w));
    short* dst = P + ((size_t)(tile * 4 + k0) * 64 + lane) * 8;
    *(short4*)(dst) = o0;
    *(short4*)(dst + 4) = o1;
}

// ---------------- MFMA fused GRU cell (bf16 in/out) ----------------
__global__ __launch_bounds__(256) void gru_mfma_k(const short* __restrict__ agg,
                                                  const short* __restrict__ hin,
                                                  short* __restrict__ hout,
                                                  const short* __restrict__ P,
                                                  const float* __restrict__ bih,
                                                  const float* __restrict__ bhh,
                                                  int nnodes) {
    __shared__ short As[16 * LDA];
    __shared__ short Hs[16 * LDA];
    const int t = threadIdx.x;
    const int mbase = blockIdx.x * 16;
    {
        int row = t >> 4, c8 = t & 15;
        int node = mbase + row;
        bf16x8 a = (bf16x8){0,0,0,0,0,0,0,0};
        bf16x8 hh = (bf16x8){0,0,0,0,0,0,0,0};
        if (node < nnodes) {
            a  = *(const bf16x8*)(agg + (size_t)node * HID + c8 * 8);
            hh = *(const bf16x8*)(hin + (size_t)node * HID + c8 * 8);
        }
        *(bf16x8*)&As[row * LDA + c8 * 8] = a;
        *(bf16x8*)&Hs[row * LDA + c8 * 8] = hh;
    }
    __syncthreads();

    const int w = t >> 6, lane = t & 63;
    const int ml = lane & 15, kq = lane >> 4;
    const int j0 = w * 32;

    f32x4 acc[12];  // idx = (mat*3 + gate)*2 + ctt
    #pragma unroll
    for (int i = 0; i < 12; ++i) acc[i] = (f32x4){0.f, 0.f, 0.f, 0.f};

    const short* Pb = P + (size_t)lane * 8;

    #pragma unroll
    for (int k0 = 0; k0 < 4; ++k0) {
        bf16x8 aa = *(const bf16x8*)&As[ml * LDA + k0 * 32 + kq * 8];
        bf16x8 ah = *(const bf16x8*)&Hs[ml * LDA + k0 * 32 + kq * 8];
        #pragma unroll
        for (int m = 0; m < 2; ++m) {
            #pragma unroll
            for (int g = 0; g < 3; ++g) {
                #pragma unroll
                for (int ctt = 0; ctt < 2; ++ctt) {
                    const int tile = m * 24 + g * 8 + (w << 1) + ctt;
                    bf16x8 bb = *(const bf16x8*)(Pb + (size_t)(tile * 4 + k0) * 512);
                    const int idx = (m * 3 + g) * 2 + ctt;
                    acc[idx] = __builtin_amdgcn_mfma_f32_16x16x32_bf16(
                        (m == 0) ? aa : ah, bb, acc[idx], 0, 0, 0);
                }
            }
        }
    }

    #pragma unroll
    for (int ctt = 0; ctt < 2; ++ctt) {
        const int col = j0 + ctt * 16 + ml;
        const float b_ir = bih[col], b_iz = bih[col + 128], b_in = bih[col + 256];
        const float b_hr = bhh[col], b_hz = bhh[col + 128], b_hn = bhh[col + 256];
        #pragma unroll
        for (int r = 0; r < 4; ++r) {
            const int row = kq * 4 + r;
            const int node = mbase + row;
            float ir = acc[0 + ctt][r] + b_ir;
            float iz = acc[2 + ctt][r] + b_iz;
            float in_ = acc[4 + ctt][r] + b_in;
            float hr = acc[6 + ctt][r] + b_hr;
            float hz = acc[8 + ctt][r] + b_hz;
            float hn = acc[10 + ctt][r] + b_hn;
            float rr = 1.f / (1.f + expf(-(ir + hr)));
            float z  = 1.f / (1.f + expf(-(iz + hz)));
            float n  = tanhf(in_ + rr * hn);
            if (node < nnodes) {
                float hval = bf2f(Hs[row * LDA + col]);
                hout[(size_t)node * HID + col] = f2bf((1.f - z) * n + z * hval);
            }
        }
    }
}

// ---------------- MFMA dense (bf16 in/out): y = x @ W.T + b ----------------
__global__ __launch_bounds__(256) void dense_mfma_k(const short* __restrict__ x,
                                                    short* __restrict__ y,
                                                    const short* __restrict__ P,
                                                    const float* __restrict__ b,
                                                    int nnodes) {
    __shared__ short Xs[16 * LDA];
    const int t = threadIdx.x;
    const int mbase = blockIdx.x * 16;
    {
        int row = t >> 4, c8 = t & 15;
        int node = mbase + row;
        bf16x8 xv = (bf16x8){0,0,0,0,0,0,0,0};
        if (node < nnodes) xv = *(const bf16x8*)(x + (size_t)node * HID + c8 * 8);
        *(bf16x8*)&Xs[row * LDA + c8 * 8] = xv;
    }
    __syncthreads();

    const int w = t >> 6, lane = t & 63;
    const int ml = lane & 15, kq = lane >> 4;
    const int j0 = w * 32;

    f32x4 acc[2];
    acc[0] = (f32x4){0.f, 0.f, 0.f, 0.f};
    acc[1] = (f32x4){0.f, 0.f, 0.f, 0.f};
    const short* Pb = P + (size_t)lane * 8;

    #pragma unroll
    for (int k0 = 0; k0 < 4; ++k0) {
        bf16x8 aa = *(const bf16x8*)&Xs[ml * LDA + k0 * 32 + kq * 8];
        #pragma unroll
        for (int ctt = 0; ctt < 2; ++ctt) {
            const int tile = (w << 1) + ctt;
            bf16x8 bb = *(const bf16x8*)(Pb + (size_t)(tile * 4 + k0) * 512);
            acc[ctt] = __builtin_amdgcn_mfma_f32_16x16x32_bf16(aa, bb, acc[ctt], 0, 0, 0);
        }
    }

    #pragma unroll
    for (int ctt = 0; ctt < 2; ++ctt) {
        const int col = j0 + ctt * 16 + ml;
        const float bias = b[col];
        #pragma unroll
        for (int r = 0; r < 4; ++r) {
            const int node = mbase + kq * 4 + r;
            if (node < nnodes)
                y[(size_t)node * HID + col] = f2bf(acc[ctt][r] + bias);
        }
    }
}

// ---------------- segment max pool, 4-way split per graph ----------------
__global__ __launch_bounds__(256) void pool_k(const short* __restrict__ xh,
                                              const int* __restrict__ batch,
                                              int nnodes, float* __restrict__ pmax) {
    const int g = blockIdx.x >> 2;
    const int p = blockIdx.x & (POOL_P - 1);
    int lo = 0, hi = nnodes;
    while (lo < hi) { int mid = (lo + hi) >> 1; if (batch[mid] < g) lo = mid + 1; else hi = mid; }
    int start = lo;
    lo = 0; hi = nnodes;
    while (lo < hi) { int mid = (lo + hi) >> 1; if (batch[mid] < g + 1) lo = mid + 1; else hi = mid; }
    int end = lo;
    int len = end - start;
    int q0 = start + (int)(((long long)len * p) / POOL_P);
    int q1 = start + (int)(((long long)len * (p + 1)) / POOL_P);

    const int rg = threadIdx.x >> 6;   // 0..3 row group
    const int j2 = threadIdx.x & 63;   // col pair
    float m0 = -INFINITY, m1 = -INFINITY;
    for (int i = q0 + rg; i < q1; i += 4) {
        unsigned int u = *(const unsigned int*)(xh + (size_t)i * HID + j2 * 2);
        m0 = fmaxf(m0, __uint_as_float(u << 16));
        m1 = fmaxf(m1, __uint_as_float(u & 0xFFFF0000u));
    }
    __shared__ float pm[4][130];
    pm[rg][j2 * 2] = m0;
    pm[rg][j2 * 2 + 1] = m1;
    __syncthreads();
    if (rg == 0) {
        float a = fmaxf(fmaxf(pm[0][j2 * 2], pm[1][j2 * 2]), fmaxf(pm[2][j2 * 2], pm[3][j2 * 2]));
        float c = fmaxf(fmaxf(pm[0][j2 * 2 + 1], pm[1][j2 * 2 + 1]), fmaxf(pm[2][j2 * 2 + 1], pm[3][j2 * 2 + 1]));
        *(float2*)(pmax + (size_t)blockIdx.x * HID + j2 * 2) = make_float2(a, c);
    }
}

// ---------------- classifier: reduce partial maxes, dot, sigmoid ----------------
__global__ __launch_bounds__(128) void clf_k(const float* __restrict__ pmax,
                                             const float* __restrict__ W,
                                             const float* __restrict__ b,
                                             float* __restrict__ out) {
    __shared__ float red[2];
    const int g = blockIdx.x;
    const int t = threadIdx.x;
    float m = -INFINITY;
    #pragma unroll
    for (int p = 0; p < POOL_P; ++p)
        m = fmaxf(m, pmax[((size_t)g * POOL_P + p) * HID + t]);
    float v = m * W[t];
    #pragma unroll
    for (int off = 32; off >= 1; off >>= 1) v += __shfl_down(v, off, 64);
    if ((t & 63) == 0) red[t >> 6] = v;
    __syncthreads();
    if (t == 0) {
        float s = red[0] + red[1] + b[0];
        out[g] = 1.f / (1.f + expf(-s));
    }
}

extern "C" void kernel_launch(void* const* d_in, const int* in_sizes, int n_in,
                              void* d_out, int out_size, void* d_ws, size_t ws_size,
                              hipStream_t stream) {
    const int* x      = (const int*)d_in[0];
    const int* ei     = (const int*)d_in[1];
    const int* batch  = (const int*)d_in[2];
    const float* emb  = (const float*)d_in[3];
    const float* Wih0 = (const float*)d_in[4];
    const float* Whh0 = (const float*)d_in[5];
    const float* bih0 = (const float*)d_in[6];
    const float* bhh0 = (const float*)d_in[7];
    const float* Wih1 = (const float*)d_in[8];
    const float* Whh1 = (const float*)d_in[9];
    const float* bih1 = (const float*)d_in[10];
    const float* bhh1 = (const float*)d_in[11];
    const float* dW   = (const float*)d_in[12];
    const float* db   = (const float*)d_in[13];
    const float* cW   = (const float*)d_in[14];
    const float* cb   = (const float*)d_in[15];

    const int N = in_sizes[0];          // 100000
    const int E = in_sizes[1] / 2;      // 1600000
    const int NG = out_size;            // 128
    const size_t NH = (size_t)N * HID;

    short* hb0 = (short*)d_ws;                       // NH bf16
    short* hb1 = hb0 + NH;                           // NH bf16 (agg)
    short* hb2 = hb1 + NH;                           // NH bf16
    short* P0  = hb2 + NH;                           // 48*4*64*8
    short* P1  = P0 + 48 * 4 * 64 * 8;
    short* Pd  = P1 + 48 * 4 * 64 * 8;               // 8*4*64*8
    float* pmax = (float*)(Pd + 8 * 4 * 64 * 8);     // NG*POOL_P*HID
    int* deg        = (int*)(pmax + (size_t)NG * POOL_P * HID);
    int* rowstart   = deg + N;                       // N+1 (padded to N+4 for alignment)
    int* cursor     = rowstart + (N + 4);            // N (16B aligned)
    int* sorted_src = cursor + N;                    // E

    const int* esrc = ei;
    const int* edst = ei + E;

    dim3 blk(256);
    int embGrid  = (N * 16 + 255) / 256;
    int edgeGrid = (E + 255) / 256;
    int tileGrid = (N + 15) / 16;
    const int NCH = 104;                // chunks per partition; grid = 8*NCH

    // weight packing (independent of data path)
    pack_k<<<48, blk, 0, stream>>>(Wih0, Whh0, P0, 24);
    pack_k<<<48, blk, 0, stream>>>(Wih1, Whh1, P1, 24);
    pack_k<<<8,  blk, 0, stream>>>(dW,   dW,   Pd, 8);

    // h = bf16(emb[x])
    embed_k<<<embGrid, blk, 0, stream>>>(x, emb, hb0, N);

    // CSR build (reused by both layers)
    hipMemsetAsync(deg, 0, (size_t)N * sizeof(int), stream);
    hist_k<<<edgeGrid, blk, 0, stream>>>(edst, deg, E);
    scan_k<<<1, dim3(1024), 0, stream>>>(deg, rowstart, cursor, N);
    fill_k<<<8 * NCH, blk, 0, stream>>>(esrc, edst, cursor, sorted_src,
                                        E, (N + 7) / 8, N, NCH);

    // layer 0
    gather_k<<<embGrid, blk, 0, stream>>>(rowstart, sorted_src, hb0, hb1, N);
    gru_mfma_k<<<tileGrid, blk, 0, stream>>>(hb1, hb0, hb2, P0, bih0, bhh0, N);

    // layer 1
    gather_k<<<embGrid, blk, 0, stream>>>(rowstart, sorted_src, hb2, hb1, N);
    gru_mfma_k<<<tileGrid, blk, 0, stream>>>(hb1, hb2, hb0, P1, bih1, bhh1, N);

    // dense
    dense_mfma_k<<<tileGrid, blk, 0, stream>>>(hb0, hb2, Pd, db, N);

    // pool + classifier
    pool_k<<<NG * POOL_P, blk, 0, stream>>>(hb2, batch, N, pmax);
    clf_k<<<NG, dim3(128), 0, stream>>>(pmax, cW, cb, (float*)d_out);
}